// Round 10
// baseline (17.177 us; speedup 1.0000x reference)
//
#include <hip/hip_runtime.h>

// SeeSawLoss, simplified:
//   loss(b,h,w) = log( sum_i exp(l[b,i,h,w]) * max(w[b,i], w[b,t]) ) - log(w[b,t]) - l[b,t,h,w]
//   out = mean over all (b,h,w);  M[i,t] = (wi>wt ? wi/wt : 1) == max(wi,wt)/wt
// B=8, N=128, H=W=128.
//
// R9 proved nontemporal loads fix L1-set aliasing of the 64KB-stride column
// walk (18.3 -> 16.5us). This round combines nt with float4 width at
// 32 waves/CU: 2048 blocks x 256 thr, 16-way class split (8 classes/thread),
// 4 pixels/thread. Two-kernel deterministic reduction (R7: fused atomics cost
// ~50us; a second dispatch is ~2-3us).

#define B_    8
#define N_    128
#define HW_   16384              // 128*128
#define NPIX  (B_ * HW_)         // 131072
#define BLOCK 256
#define PX    64                 // pixels per block
#define OCTS  16                 // class groups
#define CPT   8                  // classes per thread
#define BLOCKS_PER_B (HW_ / PX)  // 256
#define NBLOCKS (B_ * BLOCKS_PER_B)  // 2048

using v4f = __attribute__((ext_vector_type(4))) float;

__global__ __launch_bounds__(BLOCK) void seesaw_main(
    const float* __restrict__ logit,
    const int*   __restrict__ target,
    const float* __restrict__ weight,
    float*       __restrict__ partials)
{
    __shared__ float w_s[N_];
    __shared__ float sa[OCTS][PX];
    __shared__ int   t_s[PX];

    const int tid  = threadIdx.x;
    const int b    = blockIdx.x >> 8;            // / BLOCKS_PER_B
    const int pix0 = (blockIdx.x & 255) * PX;
    const int quad = (tid & 15) * 4;             // 4 consecutive pixels
    const int q    = tid >> 4;                   // class group

    if (tid < N_) w_s[tid] = weight[b * N_ + tid];
    __syncthreads();

    const int4 t4 = *(const int4*)(target + b * HW_ + pix0 + quad);
    if (q == 0) *(int4*)&t_s[quad] = t4;

    const float wt0 = w_s[t4.x], wt1 = w_s[t4.y], wt2 = w_s[t4.z], wt3 = w_s[t4.w];

    const int ibase = q * CPT;
    const float* lp = logit + (size_t)(b * N_ + ibase) * HW_ + pix0 + quad;

    float a0 = 0.f, a1 = 0.f, a2 = 0.f, a3 = 0.f;

    #pragma unroll
    for (int k = 0; k < CPT; ++k) {
        const v4f l = __builtin_nontemporal_load((const v4f*)(lp + (size_t)k * HW_));
        const float wi = w_s[ibase + k];
        a0 = fmaf(__expf(l.x), fmaxf(wi, wt0), a0);
        a1 = fmaf(__expf(l.y), fmaxf(wi, wt1), a1);
        a2 = fmaf(__expf(l.z), fmaxf(wi, wt2), a2);
        a3 = fmaf(__expf(l.w), fmaxf(wi, wt3), a3);
    }

    *(float4*)&sa[q][quad] = make_float4(a0, a1, a2, a3);
    __syncthreads();

    float loss = 0.0f;
    if (tid < PX) {                              // wave 0: one lane per pixel
        float at = 0.0f;
        #pragma unroll
        for (int k = 0; k < OCTS; ++k) at += sa[k][tid];
        const int   t  = t_s[tid];
        const float wt = w_s[t];
        const float lt = logit[(size_t)(b * N_ + t) * HW_ + pix0 + tid];  // cached gather
        loss = __logf(at) - __logf(wt) - lt;

        #pragma unroll
        for (int o = 32; o > 0; o >>= 1) loss += __shfl_down(loss, o, 64);
    }
    if (tid == 0) partials[blockIdx.x] = loss;
}

__global__ __launch_bounds__(1024) void seesaw_reduce(
    const float* __restrict__ partials,
    float*       __restrict__ out)
{
    __shared__ float red[16];
    float s = partials[threadIdx.x] + partials[threadIdx.x + 1024];

    #pragma unroll
    for (int o = 32; o > 0; o >>= 1) s += __shfl_down(s, o, 64);

    const int lane = threadIdx.x & 63;
    const int wid  = threadIdx.x >> 6;
    if (lane == 0) red[wid] = s;
    __syncthreads();

    if (threadIdx.x == 0) {
        float tot = 0.0f;
        #pragma unroll
        for (int k = 0; k < 16; ++k) tot += red[k];
        out[0] = tot * (1.0f / (float)NPIX);
    }
}

extern "C" void kernel_launch(void* const* d_in, const int* in_sizes, int n_in,
                              void* d_out, int out_size, void* d_ws, size_t ws_size,
                              hipStream_t stream)
{
    const float* logit  = (const float*)d_in[0];
    const int*   target = (const int*)  d_in[1];
    const float* weight = (const float*)d_in[2];
    // d_in[3] = epoch (unused by the reference math)

    float* partials = (float*)d_ws;   // NBLOCKS floats
    float* out      = (float*)d_out;

    seesaw_main<<<NBLOCKS, BLOCK, 0, stream>>>(logit, target, weight, partials);
    seesaw_reduce<<<1, 1024, 0, stream>>>(partials, out);
}